// Round 1
// baseline (1305.804 us; speedup 1.0000x reference)
//
#include <hip/hip_runtime.h>
#include <math.h>

#define IMG_W 128
#define HW 16384
#define NCH 128
#define NB 8
#define CSLOT 16777216   // 8*128*16384 elements (h_next slot size)

__device__ __forceinline__ float sigmoidf_(float x) { return 1.0f / (1.0f + expf(-x)); }

// ---------------- depthwise conv (K=5 or 7), LDS tiled, bias fused ----------------
template<int K>
__global__ void dw_conv_kernel(const float* __restrict__ in,    // planes (b*128+ch)*HW
                               const float* __restrict__ w,     // (128,1,K,K), pre-offset by host
                               const float* __restrict__ bias,  // pre-offset by host
                               float* __restrict__ out,         // plane (b*out_cstride + chan_off + ch)
                               int out_cstride, int chan_off)
{
    constexpr int P = K / 2;
    constexpr int T = 16;
    constexpr int L = T + 2 * P;
    __shared__ float tile[L][L + 1];
    __shared__ float wsh[K * K];

    int b  = blockIdx.z >> 7;
    int ch = blockIdx.z & 127;
    int ox = blockIdx.x * T;
    int oy = blockIdx.y * T;
    int tid = threadIdx.y * T + threadIdx.x;

    const float* plane = in + (size_t)(b * NCH + ch) * HW;
    if (tid < K * K) wsh[tid] = w[ch * K * K + tid];

    for (int idx = tid; idx < L * L; idx += 256) {
        int ly = idx / L, lx = idx % L;
        int gy = oy + ly - P, gx = ox + lx - P;
        float v = 0.f;
        if ((unsigned)gy < 128u && (unsigned)gx < 128u) v = plane[gy * IMG_W + gx];
        tile[ly][lx] = v;
    }
    __syncthreads();

    float acc = 0.f;
#pragma unroll
    for (int u = 0; u < K; ++u)
#pragma unroll
        for (int v = 0; v < K; ++v)
            acc += tile[threadIdx.y + u][threadIdx.x + v] * wsh[u * K + v];
    acc += bias[ch];
    out[((size_t)(b * out_cstride + chan_off + ch)) * HW + (oy + threadIdx.y) * IMG_W + ox + threadIdx.x] = acc;
}

// ---------------- fused pointwise GEMMs + gating + c_next + partial LN sums ----------------
// block: 256 threads computes 32 gate-channels x 64 pixels for one sample b.
// grid: (256 px-tiles, 4 gc-tiles, 8 b)
__global__ void gate_kernel(const float* __restrict__ dxh,   // (8,256,HW)
                            const float* __restrict__ dexc,  // (8,128,HW)
                            const float* __restrict__ dinh,  // (8,128,HW)
                            const float* __restrict__ Wxh,   // (384,256)
                            const float* __restrict__ bxh,   // (384)
                            const float* __restrict__ Wexc,  // (128,128)
                            const float* __restrict__ bexc,
                            const float* __restrict__ Winh,
                            const float* __restrict__ binh,
                            const float* __restrict__ cin,   // (8,128,HW)
                            float* __restrict__ out,         // d_out: [h slot][c slot]
                            float* __restrict__ partials)    // (8*1024, 2)
{
    __shared__ float sW[3][32][17];
    __shared__ float sD[16][64];
    __shared__ float rbuf[8];

    int pxT = blockIdx.x;
    int gcT = blockIdx.y;
    int b   = blockIdx.z;
    int px0 = pxT * 64;
    int gc0 = gcT * 32;
    int tid = threadIdx.x;
    int tgc = tid >> 4;   // 0..15
    int tpx = tid & 15;   // 0..15
    int gr = tgc * 2;     // row in 0..30
    int pc = tpx * 4;     // col in 0..60

    float accF[2][4] = {}, accG[2][4] = {}, accO[2][4] = {}, accE[2][4] = {}, accI[2][4] = {};

    // ---- phase 1: xh pointwise (K=256), three weight rows per gate channel ----
    for (int k0 = 0; k0 < 256; k0 += 16) {
        for (int idx = tid; idx < 1536; idx += 256) {
            int m = idx / 512, rem = idx % 512;
            int r = rem >> 4, kk = rem & 15;
            sW[m][r][kk] = Wxh[(size_t)(gc0 + r + m * 128) * 256 + k0 + kk];
        }
        for (int idx = tid; idx < 1024; idx += 256) {
            int kk = idx >> 6, p = idx & 63;
            sD[kk][p] = dxh[((size_t)(b * 256 + k0 + kk)) * HW + px0 + p];
        }
        __syncthreads();
#pragma unroll
        for (int kk = 0; kk < 16; ++kk) {
            float4 d = *(const float4*)&sD[kk][pc];
#pragma unroll
            for (int r = 0; r < 2; ++r) {
                float wf = sW[0][gr + r][kk];
                float wg = sW[1][gr + r][kk];
                float wo = sW[2][gr + r][kk];
                accF[r][0] += wf * d.x; accF[r][1] += wf * d.y; accF[r][2] += wf * d.z; accF[r][3] += wf * d.w;
                accG[r][0] += wg * d.x; accG[r][1] += wg * d.y; accG[r][2] += wg * d.z; accG[r][3] += wg * d.w;
                accO[r][0] += wo * d.x; accO[r][1] += wo * d.y; accO[r][2] += wo * d.z; accO[r][3] += wo * d.w;
            }
        }
        __syncthreads();
    }

    // ---- phase 2: exc pointwise (K=128) ----
    for (int k0 = 0; k0 < 128; k0 += 16) {
        for (int idx = tid; idx < 512; idx += 256) {
            int r = idx >> 4, kk = idx & 15;
            sW[0][r][kk] = Wexc[(size_t)(gc0 + r) * 128 + k0 + kk];
        }
        for (int idx = tid; idx < 1024; idx += 256) {
            int kk = idx >> 6, p = idx & 63;
            sD[kk][p] = dexc[((size_t)(b * 128 + k0 + kk)) * HW + px0 + p];
        }
        __syncthreads();
#pragma unroll
        for (int kk = 0; kk < 16; ++kk) {
            float4 d = *(const float4*)&sD[kk][pc];
#pragma unroll
            for (int r = 0; r < 2; ++r) {
                float we = sW[0][gr + r][kk];
                accE[r][0] += we * d.x; accE[r][1] += we * d.y; accE[r][2] += we * d.z; accE[r][3] += we * d.w;
            }
        }
        __syncthreads();
    }

    // ---- phase 3: inh pointwise (K=128) ----
    for (int k0 = 0; k0 < 128; k0 += 16) {
        for (int idx = tid; idx < 512; idx += 256) {
            int r = idx >> 4, kk = idx & 15;
            sW[0][r][kk] = Winh[(size_t)(gc0 + r) * 128 + k0 + kk];
        }
        for (int idx = tid; idx < 1024; idx += 256) {
            int kk = idx >> 6, p = idx & 63;
            sD[kk][p] = dinh[((size_t)(b * 128 + k0 + kk)) * HW + px0 + p];
        }
        __syncthreads();
#pragma unroll
        for (int kk = 0; kk < 16; ++kk) {
            float4 d = *(const float4*)&sD[kk][pc];
#pragma unroll
            for (int r = 0; r < 2; ++r) {
                float wi = sW[0][gr + r][kk];
                accI[r][0] += wi * d.x; accI[r][1] += wi * d.y; accI[r][2] += wi * d.z; accI[r][3] += wi * d.w;
            }
        }
        __syncthreads();
    }

    // ---- epilogue: gating, c_next, stash o, partial sums ----
    float lsum = 0.f, lsq = 0.f;
#pragma unroll
    for (int r = 0; r < 2; ++r) {
        int gc = gc0 + gr + r;
        float bf = bxh[gc], bg = bxh[gc + 128], bo = bxh[gc + 256];
        float be = bexc[gc], bi = binh[gc];
#pragma unroll
        for (int j = 0; j < 4; ++j) {
            int px = px0 + pc + j;
            size_t idx = ((size_t)(b * NCH + gc)) * HW + px;
            float f = sigmoidf_(accF[r][j] + bf);
            float o = sigmoidf_(accO[r][j] + bo);
            float xhor = fmaxf(accG[r][j] + bg, 0.f);
            float g = sigmoidf_(accI[r][j] + bi) * (xhor + sigmoidf_(accE[r][j] + be));
            float cn = f * cin[idx] + (1.f - f) * g;
            out[CSLOT + idx] = cn;
            out[idx] = o;            // stash o in h-slot; final kernel overwrites
            lsum += cn; lsq += cn * cn;
        }
    }

    // deterministic block reduction -> per-block partials
#pragma unroll
    for (int off = 32; off; off >>= 1) {
        lsum += __shfl_down(lsum, off);
        lsq  += __shfl_down(lsq, off);
    }
    int wid = tid >> 6;
    if ((tid & 63) == 0) { rbuf[wid * 2] = lsum; rbuf[wid * 2 + 1] = lsq; }
    __syncthreads();
    if (tid == 0) {
        float s = rbuf[0] + rbuf[2] + rbuf[4] + rbuf[6];
        float q = rbuf[1] + rbuf[3] + rbuf[5] + rbuf[7];
        int blin = b * 1024 + gcT * 256 + pxT;
        partials[blin * 2]     = s;
        partials[blin * 2 + 1] = q;
    }
}

// ---------------- per-sample LN statistics ----------------
__global__ void stats_kernel(const float* __restrict__ partials, float* __restrict__ stats)
{
    int b = blockIdx.x;
    int tid = threadIdx.x;
    float s = 0.f, q = 0.f;
    for (int i = tid; i < 1024; i += 256) {
        s += partials[(b * 1024 + i) * 2];
        q += partials[(b * 1024 + i) * 2 + 1];
    }
#pragma unroll
    for (int off = 32; off; off >>= 1) {
        s += __shfl_down(s, off);
        q += __shfl_down(q, off);
    }
    __shared__ float rb[8];
    int wid = tid >> 6;
    if ((tid & 63) == 0) { rb[wid * 2] = s; rb[wid * 2 + 1] = q; }
    __syncthreads();
    if (tid == 0) {
        float S = rb[0] + rb[2] + rb[4] + rb[6];
        float Q = rb[1] + rb[3] + rb[5] + rb[7];
        const float N = 2097152.0f;  // 128*16384
        float mean = S / N;
        float var = Q / N - mean * mean;
        stats[b * 2] = mean;
        stats[b * 2 + 1] = rsqrtf(var + 1e-5f);
    }
}

// ---------------- finalize: h_next = o * relu((c_next-mean)*rstd) ----------------
__global__ void final_kernel(float* __restrict__ out, const float* __restrict__ stats)
{
    const int n4 = CSLOT / 4;        // 4,194,304 float4s
    const int per_b = 2097152 / 4;   // 524,288 float4s per sample
    for (int i = blockIdx.x * blockDim.x + threadIdx.x; i < n4; i += gridDim.x * blockDim.x) {
        int b = i / per_b;
        float mean = stats[b * 2], rstd = stats[b * 2 + 1];
        float4 o4 = ((const float4*)out)[i];
        float4 c4 = ((const float4*)out)[CSLOT / 4 + i];
        float4 h4;
        h4.x = o4.x * fmaxf((c4.x - mean) * rstd, 0.f);
        h4.y = o4.y * fmaxf((c4.y - mean) * rstd, 0.f);
        h4.z = o4.z * fmaxf((c4.z - mean) * rstd, 0.f);
        h4.w = o4.w * fmaxf((c4.w - mean) * rstd, 0.f);
        ((float4*)out)[i] = h4;
    }
}

extern "C" void kernel_launch(void* const* d_in, const int* in_sizes, int n_in,
                              void* d_out, int out_size, void* d_ws, size_t ws_size,
                              hipStream_t stream)
{
    const float* x        = (const float*)d_in[0];
    const float* h        = (const float*)d_in[1];
    const float* c        = (const float*)d_in[2];
    const float* w_xh_dw  = (const float*)d_in[3];
    const float* b_xh_dw  = (const float*)d_in[4];
    const float* w_xh_pw  = (const float*)d_in[5];
    const float* b_xh_pw  = (const float*)d_in[6];
    const float* w_exc_dw = (const float*)d_in[7];
    const float* b_exc_dw = (const float*)d_in[8];
    const float* w_exc_pw = (const float*)d_in[9];
    const float* b_exc_pw = (const float*)d_in[10];
    const float* w_inh_dw = (const float*)d_in[11];
    const float* b_inh_dw = (const float*)d_in[12];
    const float* w_inh_pw = (const float*)d_in[13];
    const float* b_inh_pw = (const float*)d_in[14];

    float* out = (float*)d_out;
    float* ws  = (float*)d_ws;

    float* dxh      = ws;                          // 33,554,432 floats (8,256,HW)
    float* dexc     = ws + 33554432;               // 16,777,216
    float* dinh     = ws + 33554432 + 16777216;    // 16,777,216
    float* partials = ws + 67108864;               // 16,384 floats
    float* stats    = partials + 16384;            // 16 floats

    dim3 dwgrid(8, 8, 1024), dwblk(16, 16, 1);
    // xh depthwise: x -> channels 0..127, h -> channels 128..255 (concat fused)
    dw_conv_kernel<5><<<dwgrid, dwblk, 0, stream>>>(x, w_xh_dw,            b_xh_dw,       dxh, 256, 0);
    dw_conv_kernel<5><<<dwgrid, dwblk, 0, stream>>>(h, w_xh_dw + 128 * 25, b_xh_dw + 128, dxh, 256, 128);
    dw_conv_kernel<7><<<dwgrid, dwblk, 0, stream>>>(h, w_exc_dw,           b_exc_dw,      dexc, 128, 0);
    dw_conv_kernel<5><<<dwgrid, dwblk, 0, stream>>>(h, w_inh_dw,           b_inh_dw,      dinh, 128, 0);

    gate_kernel<<<dim3(256, 4, 8), dim3(256), 0, stream>>>(
        dxh, dexc, dinh, w_xh_pw, b_xh_pw, w_exc_pw, b_exc_pw, w_inh_pw, b_inh_pw,
        c, out, partials);

    stats_kernel<<<dim3(8), dim3(256), 0, stream>>>(partials, stats);
    final_kernel<<<dim3(2048), dim3(256), 0, stream>>>(out, stats);
}

// Round 2
// 653.318 us; speedup vs baseline: 1.9987x; 1.9987x over previous
//
#include <hip/hip_runtime.h>
#include <math.h>

#define IMG_W 128
#define HW 16384
#define NCH 128
#define NB 8
#define CSLOT 16777216   // 8*128*16384 elements (h_next slot size)

typedef __attribute__((ext_vector_type(8))) short bf16x8;
typedef __attribute__((ext_vector_type(16))) float f32x16;
typedef __attribute__((ext_vector_type(4))) unsigned short us4;

__device__ __forceinline__ float sigmoidf_(float x) { return 1.0f / (1.0f + expf(-x)); }

__device__ __forceinline__ unsigned short f2bf(float f) {
    union { float f; unsigned int u; } x; x.f = f;
    unsigned int r = x.u + 0x7fffu + ((x.u >> 16) & 1u);   // RNE
    return (unsigned short)(r >> 16);
}

// ---------------- depthwise conv (K=5 or 7), LDS tiled, bias fused, bf16 out ----------------
template<int K>
__global__ void dw_conv_kernel(const float* __restrict__ in,    // planes (b*128+ch)*HW
                               const float* __restrict__ w,     // (128,1,K,K), pre-offset by host
                               const float* __restrict__ bias,  // pre-offset by host
                               unsigned short* __restrict__ out,// plane (b*out_cstride + chan_off + ch), bf16
                               int out_cstride, int chan_off)
{
    constexpr int P = K / 2;
    constexpr int T = 16;
    constexpr int L = T + 2 * P;
    __shared__ float tile[L][L + 1];
    __shared__ float wsh[K * K];

    int b  = blockIdx.z >> 7;
    int ch = blockIdx.z & 127;
    int ox = blockIdx.x * T;
    int oy = blockIdx.y * T;
    int tid = threadIdx.y * T + threadIdx.x;

    const float* plane = in + (size_t)(b * NCH + ch) * HW;
    if (tid < K * K) wsh[tid] = w[ch * K * K + tid];

    for (int idx = tid; idx < L * L; idx += 256) {
        int ly = idx / L, lx = idx % L;
        int gy = oy + ly - P, gx = ox + lx - P;
        float v = 0.f;
        if ((unsigned)gy < 128u && (unsigned)gx < 128u) v = plane[gy * IMG_W + gx];
        tile[ly][lx] = v;
    }
    __syncthreads();

    float acc = 0.f;
#pragma unroll
    for (int u = 0; u < K; ++u)
#pragma unroll
        for (int v = 0; v < K; ++v)
            acc += tile[threadIdx.y + u][threadIdx.x + v] * wsh[u * K + v];
    acc += bias[ch];
    out[((size_t)(b * out_cstride + chan_off + ch)) * HW + (oy + threadIdx.y) * IMG_W + ox + threadIdx.x] = f2bf(acc);
}

// ---------------- pointwise weights fp32 -> bf16 ----------------
// wbf layout: [0,98304) = Wxh (384x256); [98304,114688) = Wexc (128x128); [114688,131072) = Winh
__global__ void wconv_kernel(const float* __restrict__ Wxh, const float* __restrict__ Wexc,
                             const float* __restrict__ Winh, unsigned short* __restrict__ wbf)
{
    int i = blockIdx.x * 256 + threadIdx.x;
    if (i < 98304)       wbf[i] = f2bf(Wxh[i]);
    else if (i < 114688) wbf[i] = f2bf(Wexc[i - 98304]);
    else if (i < 131072) wbf[i] = f2bf(Winh[i - 114688]);
}

// ---------------- fused MFMA pointwise GEMMs + gating + c_next + partial LN sums ----------------
// block: 256 threads = 4 waves. Output tile: 32 gate-channels x 128 px (wave w -> px sub-tile w*32).
// 1-D grid 4096, XCD-swizzled: orig = b*512 + pxT*4 + gcT.
__global__ void gate_kernel(const unsigned short* __restrict__ dxh,   // (8,256,HW) bf16
                            const unsigned short* __restrict__ dexc,  // (8,128,HW) bf16
                            const unsigned short* __restrict__ dinh,  // (8,128,HW) bf16
                            const unsigned short* __restrict__ wbf,   // bf16 pointwise weights
                            const float* __restrict__ bxh,            // (384)
                            const float* __restrict__ bexc,
                            const float* __restrict__ binh,
                            const float* __restrict__ cin,            // (8,128,HW) fp32
                            float* __restrict__ out,                  // d_out: [h slot][c slot]
                            float* __restrict__ partials)             // (8*512, 2)
{
    __shared__ unsigned int Bt[4096];   // 128 px rows x 128B (64 k bf16), rotate-swizzled
    __shared__ float rbuf[8];

    int d = blockIdx.x;
    int orig = (d & 7) * 512 + (d >> 3);     // XCD swizzle: consecutive orig on same XCD
    int b   = orig >> 9;
    int pxT = (orig >> 2) & 127;
    int gcT = orig & 3;
    int px0 = pxT * 128;
    int gc0 = gcT * 32;

    int tid  = threadIdx.x;
    int lane = tid & 63;
    int w    = tid >> 6;
    int hi   = lane >> 5;
    int lrow = lane & 31;
    int pxl  = (w << 5) + lrow;              // 0..127 within px tile

    f32x16 accF = {}, accG = {}, accO = {}, accE = {}, accI = {};

    const unsigned short* Wexc = wbf + 98304;
    const unsigned short* Winh = wbf + 114688;

    // ================= phase 1: xh GEMM, K=256 (4 chunks of 64) =================
    {
        const unsigned short* D = dxh + (size_t)b * 256 * HW + px0;
        for (int c0 = 0; c0 < 256; c0 += 64) {
            __syncthreads();
            // stage 64k x 128px, k-pairs packed into b32, rotate swizzle on (px>>2)
            const unsigned short* base = D + (size_t)c0 * HW;
#pragma unroll
            for (int c = 0; c < 4; ++c) {
                int kp = (tid >> 5) + c * 8;        // k-pair index 0..31
                int q  = tid & 31;                  // px quad
                const unsigned short* r0 = base + (size_t)(2 * kp) * HW + q * 4;
                us4 a = *(const us4*)r0;
                us4 bb = *(const us4*)(r0 + HW);
#pragma unroll
                for (int j = 0; j < 4; ++j) {
                    int px = q * 4 + j;
                    int slotp = ((kp >> 2) + (px >> 2)) & 7;
                    int word = px * 32 + slotp * 4 + (kp & 3);
                    Bt[word] = (unsigned int)(unsigned short)a[j] | ((unsigned int)(unsigned short)bb[j] << 16);
                }
            }
            __syncthreads();
#pragma unroll
            for (int ks = 0; ks < 4; ++ks) {
                int slotp = ((ks * 2 + hi) + (pxl >> 2)) & 7;
                bf16x8 bfrag = *(const bf16x8*)&Bt[pxl * 32 + slotp * 4];
                int kg = c0 + ks * 16 + hi * 8;
                size_t ar = (size_t)(gc0 + lrow) * 256 + kg;
                bf16x8 aF = *(const bf16x8*)&wbf[ar];
                bf16x8 aG = *(const bf16x8*)&wbf[ar + 128 * 256];
                bf16x8 aO = *(const bf16x8*)&wbf[ar + 256 * 256];
                accF = __builtin_amdgcn_mfma_f32_32x32x16_bf16(aF, bfrag, accF, 0, 0, 0);
                accG = __builtin_amdgcn_mfma_f32_32x32x16_bf16(aG, bfrag, accG, 0, 0, 0);
                accO = __builtin_amdgcn_mfma_f32_32x32x16_bf16(aO, bfrag, accO, 0, 0, 0);
            }
        }
    }

    // ================= phase 2: exc GEMM, K=128 (2 chunks) =================
    {
        const unsigned short* D = dexc + (size_t)b * 128 * HW + px0;
        for (int c0 = 0; c0 < 128; c0 += 64) {
            __syncthreads();
            const unsigned short* base = D + (size_t)c0 * HW;
#pragma unroll
            for (int c = 0; c < 4; ++c) {
                int kp = (tid >> 5) + c * 8;
                int q  = tid & 31;
                const unsigned short* r0 = base + (size_t)(2 * kp) * HW + q * 4;
                us4 a = *(const us4*)r0;
                us4 bb = *(const us4*)(r0 + HW);
#pragma unroll
                for (int j = 0; j < 4; ++j) {
                    int px = q * 4 + j;
                    int slotp = ((kp >> 2) + (px >> 2)) & 7;
                    int word = px * 32 + slotp * 4 + (kp & 3);
                    Bt[word] = (unsigned int)(unsigned short)a[j] | ((unsigned int)(unsigned short)bb[j] << 16);
                }
            }
            __syncthreads();
#pragma unroll
            for (int ks = 0; ks < 4; ++ks) {
                int slotp = ((ks * 2 + hi) + (pxl >> 2)) & 7;
                bf16x8 bfrag = *(const bf16x8*)&Bt[pxl * 32 + slotp * 4];
                int kg = c0 + ks * 16 + hi * 8;
                bf16x8 aE = *(const bf16x8*)&Wexc[(size_t)(gc0 + lrow) * 128 + kg];
                accE = __builtin_amdgcn_mfma_f32_32x32x16_bf16(aE, bfrag, accE, 0, 0, 0);
            }
        }
    }

    // ================= phase 3: inh GEMM, K=128 (2 chunks) =================
    {
        const unsigned short* D = dinh + (size_t)b * 128 * HW + px0;
        for (int c0 = 0; c0 < 128; c0 += 64) {
            __syncthreads();
            const unsigned short* base = D + (size_t)c0 * HW;
#pragma unroll
            for (int c = 0; c < 4; ++c) {
                int kp = (tid >> 5) + c * 8;
                int q  = tid & 31;
                const unsigned short* r0 = base + (size_t)(2 * kp) * HW + q * 4;
                us4 a = *(const us4*)r0;
                us4 bb = *(const us4*)(r0 + HW);
#pragma unroll
                for (int j = 0; j < 4; ++j) {
                    int px = q * 4 + j;
                    int slotp = ((kp >> 2) + (px >> 2)) & 7;
                    int word = px * 32 + slotp * 4 + (kp & 3);
                    Bt[word] = (unsigned int)(unsigned short)a[j] | ((unsigned int)(unsigned short)bb[j] << 16);
                }
            }
            __syncthreads();
#pragma unroll
            for (int ks = 0; ks < 4; ++ks) {
                int slotp = ((ks * 2 + hi) + (pxl >> 2)) & 7;
                bf16x8 bfrag = *(const bf16x8*)&Bt[pxl * 32 + slotp * 4];
                int kg = c0 + ks * 16 + hi * 8;
                bf16x8 aI = *(const bf16x8*)&Winh[(size_t)(gc0 + lrow) * 128 + kg];
                accI = __builtin_amdgcn_mfma_f32_32x32x16_bf16(aI, bfrag, accI, 0, 0, 0);
            }
        }
    }

    // ================= epilogue: gating, c_next, stash o, partial LN sums =================
    float lsum = 0.f, lsq = 0.f;
#pragma unroll
    for (int r = 0; r < 16; ++r) {
        int row = (r & 3) + 8 * (r >> 2) + 4 * hi;   // verified 32x32 C/D map
        int gc = gc0 + row;
        size_t idx = ((size_t)(b * NCH + gc)) * HW + px0 + pxl;
        float f    = sigmoidf_(accF[r] + bxh[gc]);
        float o    = sigmoidf_(accO[r] + bxh[gc + 256]);
        float xhor = fmaxf(accG[r] + bxh[gc + 128], 0.f);
        float g    = sigmoidf_(accI[r] + binh[gc]) * (xhor + sigmoidf_(accE[r] + bexc[gc]));
        float cn   = f * cin[idx] + (1.f - f) * g;
        out[CSLOT + idx] = cn;
        out[idx] = o;            // stash o in h-slot; final kernel overwrites
        lsum += cn; lsq += cn * cn;
    }

#pragma unroll
    for (int off = 32; off; off >>= 1) {
        lsum += __shfl_down(lsum, off);
        lsq  += __shfl_down(lsq, off);
    }
    if ((tid & 63) == 0) { rbuf[w * 2] = lsum; rbuf[w * 2 + 1] = lsq; }
    __syncthreads();
    if (tid == 0) {
        float s = rbuf[0] + rbuf[2] + rbuf[4] + rbuf[6];
        float q = rbuf[1] + rbuf[3] + rbuf[5] + rbuf[7];
        int blin = b * 512 + gcT * 128 + pxT;
        partials[blin * 2]     = s;
        partials[blin * 2 + 1] = q;
    }
}

// ---------------- per-sample LN statistics ----------------
__global__ void stats_kernel(const float* __restrict__ partials, float* __restrict__ stats)
{
    int b = blockIdx.x;
    int tid = threadIdx.x;
    float s = 0.f, q = 0.f;
    for (int i = tid; i < 512; i += 256) {
        s += partials[(b * 512 + i) * 2];
        q += partials[(b * 512 + i) * 2 + 1];
    }
#pragma unroll
    for (int off = 32; off; off >>= 1) {
        s += __shfl_down(s, off);
        q += __shfl_down(q, off);
    }
    __shared__ float rb[8];
    int wid = tid >> 6;
    if ((tid & 63) == 0) { rb[wid * 2] = s; rb[wid * 2 + 1] = q; }
    __syncthreads();
    if (tid == 0) {
        float S = rb[0] + rb[2] + rb[4] + rb[6];
        float Q = rb[1] + rb[3] + rb[5] + rb[7];
        const float N = 2097152.0f;  // 128*16384
        float mean = S / N;
        float var = Q / N - mean * mean;
        stats[b * 2] = mean;
        stats[b * 2 + 1] = rsqrtf(var + 1e-5f);
    }
}

// ---------------- finalize: h_next = o * relu((c_next-mean)*rstd) ----------------
__global__ void final_kernel(float* __restrict__ out, const float* __restrict__ stats)
{
    const int n4 = CSLOT / 4;
    const int per_b = 2097152 / 4;
    for (int i = blockIdx.x * blockDim.x + threadIdx.x; i < n4; i += gridDim.x * blockDim.x) {
        int b = i / per_b;
        float mean = stats[b * 2], rstd = stats[b * 2 + 1];
        float4 o4 = ((const float4*)out)[i];
        float4 c4 = ((const float4*)out)[CSLOT / 4 + i];
        float4 h4;
        h4.x = o4.x * fmaxf((c4.x - mean) * rstd, 0.f);
        h4.y = o4.y * fmaxf((c4.y - mean) * rstd, 0.f);
        h4.z = o4.z * fmaxf((c4.z - mean) * rstd, 0.f);
        h4.w = o4.w * fmaxf((c4.w - mean) * rstd, 0.f);
        ((float4*)out)[i] = h4;
    }
}

extern "C" void kernel_launch(void* const* d_in, const int* in_sizes, int n_in,
                              void* d_out, int out_size, void* d_ws, size_t ws_size,
                              hipStream_t stream)
{
    const float* x        = (const float*)d_in[0];
    const float* h        = (const float*)d_in[1];
    const float* c        = (const float*)d_in[2];
    const float* w_xh_dw  = (const float*)d_in[3];
    const float* b_xh_dw  = (const float*)d_in[4];
    const float* w_xh_pw  = (const float*)d_in[5];
    const float* b_xh_pw  = (const float*)d_in[6];
    const float* w_exc_dw = (const float*)d_in[7];
    const float* b_exc_dw = (const float*)d_in[8];
    const float* w_exc_pw = (const float*)d_in[9];
    const float* b_exc_pw = (const float*)d_in[10];
    const float* w_inh_dw = (const float*)d_in[11];
    const float* b_inh_dw = (const float*)d_in[12];
    const float* w_inh_pw = (const float*)d_in[13];
    const float* b_inh_pw = (const float*)d_in[14];

    float* out = (float*)d_out;
    unsigned short* wsu = (unsigned short*)d_ws;

    // bf16 workspace layout (ushort offsets)
    unsigned short* dxh  = wsu;                       // 33,554,432 ushort (8,256,HW)
    unsigned short* dexc = wsu + 33554432;            // 16,777,216
    unsigned short* dinh = wsu + 50331648;            // 16,777,216
    unsigned short* wbf  = wsu + 67108864;            // 131,072
    float* partials = (float*)(wsu + 67239936);       // 8,192 floats (16B aligned)
    float* stats    = partials + 8192;                // 16 floats

    wconv_kernel<<<dim3(512), dim3(256), 0, stream>>>(w_xh_pw, w_exc_pw, w_inh_pw, wbf);

    dim3 dwgrid(8, 8, 1024), dwblk(16, 16, 1);
    dw_conv_kernel<5><<<dwgrid, dwblk, 0, stream>>>(x, w_xh_dw,            b_xh_dw,       dxh, 256, 0);
    dw_conv_kernel<5><<<dwgrid, dwblk, 0, stream>>>(h, w_xh_dw + 128 * 25, b_xh_dw + 128, dxh, 256, 128);
    dw_conv_kernel<7><<<dwgrid, dwblk, 0, stream>>>(h, w_exc_dw,           b_exc_dw,      dexc, 128, 0);
    dw_conv_kernel<5><<<dwgrid, dwblk, 0, stream>>>(h, w_inh_dw,           b_inh_dw,      dinh, 128, 0);

    gate_kernel<<<dim3(4096), dim3(256), 0, stream>>>(
        dxh, dexc, dinh, wbf, b_xh_pw, b_exc_pw, b_inh_pw, c, out, partials);

    stats_kernel<<<dim3(8), dim3(256), 0, stream>>>(partials, stats);
    final_kernel<<<dim3(2048), dim3(256), 0, stream>>>(out, stats);
}

// Round 3
// 451.466 us; speedup vs baseline: 2.8924x; 1.4471x over previous
//
#include <hip/hip_runtime.h>
#include <math.h>

#define IMG_W 128
#define HW 16384
#define NCH 128
#define CSLOT 16777216   // 8*128*16384 elements (h_next slot size)

typedef __attribute__((ext_vector_type(8))) short bf16x8;
typedef __attribute__((ext_vector_type(16))) float f32x16;
typedef __attribute__((ext_vector_type(8))) unsigned short us8;

__device__ __forceinline__ float sigmoidf_(float x) { return 1.0f / (1.0f + expf(-x)); }

__device__ __forceinline__ unsigned short f2bf(float f) {
    union { float f; unsigned int u; } x; x.f = f;
    unsigned int r = x.u + 0x7fffu + ((x.u >> 16) & 1u);   // RNE
    return (unsigned short)(r >> 16);
}
__device__ __forceinline__ float bf2f(unsigned short s) {
    union { unsigned int u; float f; } x; x.u = ((unsigned int)s) << 16; return x.f;
}

// ---------------- x depthwise conv 5x5, 64x32 tile, 8px/thread, bf16 out ----------------
__global__ __launch_bounds__(256) void conv_x_kernel(const float* __restrict__ in,
    const float* __restrict__ w, const float* __restrict__ bias,
    unsigned short* __restrict__ dxh)   // channels 0..127 of (8,256,HW)
{
    __shared__ float tile[36][72];
    __shared__ float wsh[26];
    int b = blockIdx.z, ch = blockIdx.y;
    int tx0 = (blockIdx.x & 1) * 64, ty0 = (blockIdx.x >> 1) * 32;
    int tid = threadIdx.x;
    const float* plane = in + (size_t)(b * NCH + ch) * HW;
    if (tid < 25) wsh[tid] = w[ch * 25 + tid];
    if (tid == 25) wsh[25] = bias[ch];
    for (int idx = tid; idx < 36 * 68; idx += 256) {
        int ly = idx / 68, lx = idx % 68;
        int gy = ty0 + ly - 2, gx = tx0 + lx - 2;
        tile[ly][lx] = ((unsigned)gy < 128u && (unsigned)gx < 128u) ? plane[gy * IMG_W + gx] : 0.f;
    }
    __syncthreads();
    int ty = tid >> 3, s = (tid & 7) * 8;
    float acc[8] = {};
#pragma unroll
    for (int u = 0; u < 5; ++u) {
        float win[12];
        *(float4*)&win[0] = *(const float4*)&tile[ty + u][s];
        *(float4*)&win[4] = *(const float4*)&tile[ty + u][s + 4];
        *(float4*)&win[8] = *(const float4*)&tile[ty + u][s + 8];
#pragma unroll
        for (int v = 0; v < 5; ++v) {
            float wv = wsh[u * 5 + v];
#pragma unroll
            for (int p = 0; p < 8; ++p) acc[p] += win[p + v] * wv;
        }
    }
    float bv = wsh[25];
    us8 o;
#pragma unroll
    for (int p = 0; p < 8; ++p) o[p] = f2bf(acc[p] + bv);
    *(us8*)&dxh[((size_t)(b * 256 + ch)) * HW + (ty0 + ty) * IMG_W + tx0 + s] = o;
}

// ---------------- fused h depthwise convs: 7x7(exc) + 5x5(xh h-part) + 5x5(inh) ----------------
__global__ __launch_bounds__(256) void conv_h_kernel(const float* __restrict__ in,
    const float* __restrict__ w7,  const float* __restrict__ b7,
    const float* __restrict__ w5x, const float* __restrict__ b5x,
    const float* __restrict__ w5i, const float* __restrict__ b5i,
    unsigned short* __restrict__ dxh, unsigned short* __restrict__ dexc,
    unsigned short* __restrict__ dinh)
{
    __shared__ float tile[38][72];
    __shared__ float wsh[102];
    int b = blockIdx.z, ch = blockIdx.y;
    int tx0 = (blockIdx.x & 1) * 64, ty0 = (blockIdx.x >> 1) * 32;
    int tid = threadIdx.x;
    const float* plane = in + (size_t)(b * NCH + ch) * HW;
    if (tid < 49)       wsh[tid] = w7[ch * 49 + tid];
    else if (tid < 74)  wsh[tid] = w5x[ch * 25 + tid - 49];
    else if (tid < 99)  wsh[tid] = w5i[ch * 25 + tid - 74];
    else if (tid == 99)  wsh[99]  = b7[ch];
    else if (tid == 100) wsh[100] = b5x[ch];
    else if (tid == 101) wsh[101] = b5i[ch];
    for (int idx = tid; idx < 38 * 70; idx += 256) {
        int ly = idx / 70, lx = idx % 70;
        int gy = ty0 + ly - 3, gx = tx0 + lx - 3;
        tile[ly][lx] = ((unsigned)gy < 128u && (unsigned)gx < 128u) ? plane[gy * IMG_W + gx] : 0.f;
    }
    __syncthreads();
    int ty = tid >> 3, s = (tid & 7) * 8;
    float a7[8] = {}, ax[8] = {}, ai[8] = {};
#pragma unroll
    for (int u = 0; u < 7; ++u) {
        float win[16];
        *(float4*)&win[0]  = *(const float4*)&tile[ty + u][s];
        *(float4*)&win[4]  = *(const float4*)&tile[ty + u][s + 4];
        *(float4*)&win[8]  = *(const float4*)&tile[ty + u][s + 8];
        *(float4*)&win[12] = *(const float4*)&tile[ty + u][s + 12];
#pragma unroll
        for (int v = 0; v < 7; ++v) {
            float wv = wsh[u * 7 + v];
#pragma unroll
            for (int p = 0; p < 8; ++p) a7[p] += win[p + v] * wv;
        }
        if (u >= 1 && u <= 5) {
#pragma unroll
            for (int v = 0; v < 5; ++v) {
                float wx = wsh[49 + (u - 1) * 5 + v];
                float wi = wsh[74 + (u - 1) * 5 + v];
#pragma unroll
                for (int p = 0; p < 8; ++p) {
                    ax[p] += win[p + v + 1] * wx;
                    ai[p] += win[p + v + 1] * wi;
                }
            }
        }
    }
    float b7v = wsh[99], bxv = wsh[100], biv = wsh[101];
    size_t pxoff = (size_t)(ty0 + ty) * IMG_W + tx0 + s;
    us8 oE, oX, oI;
#pragma unroll
    for (int p = 0; p < 8; ++p) {
        oE[p] = f2bf(a7[p] + b7v);
        oX[p] = f2bf(ax[p] + bxv);
        oI[p] = f2bf(ai[p] + biv);
    }
    *(us8*)&dexc[((size_t)(b * 128 + ch)) * HW + pxoff] = oE;
    *(us8*)&dxh [((size_t)(b * 256 + 128 + ch)) * HW + pxoff] = oX;
    *(us8*)&dinh[((size_t)(b * 128 + ch)) * HW + pxoff] = oI;
}

// ---------------- pointwise weights fp32 -> bf16 ----------------
__global__ void wconv_kernel(const float* __restrict__ Wxh, const float* __restrict__ Wexc,
                             const float* __restrict__ Winh, unsigned short* __restrict__ wbf)
{
    int i = blockIdx.x * 256 + threadIdx.x;
    if (i < 98304)       wbf[i] = f2bf(Wxh[i]);
    else if (i < 114688) wbf[i] = f2bf(Wexc[i - 98304]);
    else if (i < 131072) wbf[i] = f2bf(Winh[i - 114688]);
}

// ---------------- gate kernel helpers ----------------
// Stage 64k x 128px chunk as packed k-pair words: Bt[kp*128 + px] = {k=2kp lo16, k=2kp+1 hi16}
__device__ __forceinline__ void stage_chunk(const unsigned short* __restrict__ base,
                                            unsigned int* Bt, int tid)
{
#pragma unroll
    for (int u = 0; u < 2; ++u) {
        int uid = tid + u * 256;
        int kp = uid >> 4, po = uid & 15;
        const unsigned short* r0 = base + (size_t)(2 * kp) * HW + po * 8;
        us8 a = *(const us8*)r0;
        us8 c = *(const us8*)(r0 + HW);
        unsigned int w[8];
#pragma unroll
        for (int j = 0; j < 8; ++j) w[j] = (unsigned int)a[j] | ((unsigned int)c[j] << 16);
        uint4* dst = (uint4*)&Bt[kp * 128 + po * 8];
        dst[0] = make_uint4(w[0], w[1], w[2], w[3]);
        dst[1] = make_uint4(w[4], w[5], w[6], w[7]);
    }
}

__device__ __forceinline__ bf16x8 read_bfrag(const unsigned int* Bt, int kp0, int pxl)
{
    union { unsigned int u[4]; bf16x8 v; } t;
#pragma unroll
    for (int i = 0; i < 4; ++i) t.u[i] = Bt[(kp0 + i) * 128 + pxl];
    return t.v;
}

// ---------------- fused MFMA pointwise GEMMs + gating + c_next + partial LN sums ----------------
// block: 256 threads = 4 waves. Output tile: 32 gate-channels x 128 px (wave w -> px sub-tile w*32).
// 1-D grid 4096, XCD-swizzled: orig = b*512 + pxT*4 + gcT (4 gcT siblings adjacent on one XCD).
__global__ __launch_bounds__(256) void gate_kernel(
                            const unsigned short* __restrict__ dxh,   // (8,256,HW) bf16
                            const unsigned short* __restrict__ dexc,  // (8,128,HW) bf16
                            const unsigned short* __restrict__ dinh,  // (8,128,HW) bf16
                            const unsigned short* __restrict__ wbf,   // bf16 pointwise weights
                            const float* __restrict__ bxh,
                            const float* __restrict__ bexc,
                            const float* __restrict__ binh,
                            const float* __restrict__ cin,            // (8,128,HW) fp32
                            float* __restrict__ out,                  // d_out: [h slot][c slot]
                            unsigned short* __restrict__ obuf,        // (8,128,HW) bf16 o-gate stash
                            float* __restrict__ partials)             // (8*512, 2)
{
    __shared__ __align__(16) unsigned int Bt[4096];   // [32 kp][128 px]
    __shared__ float rbuf[8];

    int d = blockIdx.x;
    int orig = (d & 7) * 512 + (d >> 3);
    int b   = orig >> 9;
    int pxT = (orig >> 2) & 127;
    int gcT = orig & 3;
    int px0 = pxT * 128;
    int gc0 = gcT * 32;

    int tid  = threadIdx.x;
    int lane = tid & 63;
    int w    = tid >> 6;
    int hi   = lane >> 5;
    int lrow = lane & 31;
    int pxl  = (w << 5) + lrow;

    f32x16 accF = {}, accG = {}, accO = {}, accE = {}, accI = {};

    const unsigned short* Wexc = wbf + 98304;
    const unsigned short* Winh = wbf + 114688;

    // ---- phase 1: xh GEMM, K=256 ----
    {
        const unsigned short* D = dxh + (size_t)b * 256 * HW + px0;
        for (int c0 = 0; c0 < 256; c0 += 64) {
            __syncthreads();
            stage_chunk(D + (size_t)c0 * HW, Bt, tid);
            __syncthreads();
#pragma unroll
            for (int ks = 0; ks < 4; ++ks) {
                bf16x8 bfrag = read_bfrag(Bt, ks * 8 + hi * 4, pxl);
                int kg = c0 + ks * 16 + hi * 8;
                size_t ar = (size_t)(gc0 + lrow) * 256 + kg;
                bf16x8 aF = *(const bf16x8*)&wbf[ar];
                bf16x8 aG = *(const bf16x8*)&wbf[ar + 32768];
                bf16x8 aO = *(const bf16x8*)&wbf[ar + 65536];
                accF = __builtin_amdgcn_mfma_f32_32x32x16_bf16(aF, bfrag, accF, 0, 0, 0);
                accG = __builtin_amdgcn_mfma_f32_32x32x16_bf16(aG, bfrag, accG, 0, 0, 0);
                accO = __builtin_amdgcn_mfma_f32_32x32x16_bf16(aO, bfrag, accO, 0, 0, 0);
            }
        }
    }
    // ---- phase 2: exc GEMM, K=128 ----
    {
        const unsigned short* D = dexc + (size_t)b * 128 * HW + px0;
        for (int c0 = 0; c0 < 128; c0 += 64) {
            __syncthreads();
            stage_chunk(D + (size_t)c0 * HW, Bt, tid);
            __syncthreads();
#pragma unroll
            for (int ks = 0; ks < 4; ++ks) {
                bf16x8 bfrag = read_bfrag(Bt, ks * 8 + hi * 4, pxl);
                int kg = c0 + ks * 16 + hi * 8;
                bf16x8 aE = *(const bf16x8*)&Wexc[(size_t)(gc0 + lrow) * 128 + kg];
                accE = __builtin_amdgcn_mfma_f32_32x32x16_bf16(aE, bfrag, accE, 0, 0, 0);
            }
        }
    }
    // ---- phase 3: inh GEMM, K=128 ----
    {
        const unsigned short* D = dinh + (size_t)b * 128 * HW + px0;
        for (int c0 = 0; c0 < 128; c0 += 64) {
            __syncthreads();
            stage_chunk(D + (size_t)c0 * HW, Bt, tid);
            __syncthreads();
#pragma unroll
            for (int ks = 0; ks < 4; ++ks) {
                bf16x8 bfrag = read_bfrag(Bt, ks * 8 + hi * 4, pxl);
                int kg = c0 + ks * 16 + hi * 8;
                bf16x8 aI = *(const bf16x8*)&Winh[(size_t)(gc0 + lrow) * 128 + kg];
                accI = __builtin_amdgcn_mfma_f32_32x32x16_bf16(aI, bfrag, accI, 0, 0, 0);
            }
        }
    }

    // ---- epilogue: gating, c_next, stash o (bf16), partial LN sums ----
    float lsum = 0.f, lsq = 0.f;
#pragma unroll
    for (int r = 0; r < 16; ++r) {
        int row = (r & 3) + 8 * (r >> 2) + 4 * hi;   // verified 32x32 C/D map
        int gc = gc0 + row;
        size_t idx = ((size_t)(b * NCH + gc)) * HW + px0 + pxl;
        float f    = sigmoidf_(accF[r] + bxh[gc]);
        float o    = sigmoidf_(accO[r] + bxh[gc + 256]);
        float xhor = fmaxf(accG[r] + bxh[gc + 128], 0.f);
        float g    = sigmoidf_(accI[r] + binh[gc]) * (xhor + sigmoidf_(accE[r] + bexc[gc]));
        float cn   = f * cin[idx] + (1.f - f) * g;
        out[CSLOT + idx] = cn;
        obuf[idx] = f2bf(o);
        lsum += cn; lsq += cn * cn;
    }

#pragma unroll
    for (int off = 32; off; off >>= 1) {
        lsum += __shfl_down(lsum, off);
        lsq  += __shfl_down(lsq, off);
    }
    if ((tid & 63) == 0) { rbuf[w * 2] = lsum; rbuf[w * 2 + 1] = lsq; }
    __syncthreads();
    if (tid == 0) {
        float s = rbuf[0] + rbuf[2] + rbuf[4] + rbuf[6];
        float q = rbuf[1] + rbuf[3] + rbuf[5] + rbuf[7];
        int blin = b * 512 + gcT * 128 + pxT;
        partials[blin * 2]     = s;
        partials[blin * 2 + 1] = q;
    }
}

// ---------------- per-sample LN statistics ----------------
__global__ void stats_kernel(const float* __restrict__ partials, float* __restrict__ stats)
{
    int b = blockIdx.x;
    int tid = threadIdx.x;
    float s = 0.f, q = 0.f;
    for (int i = tid; i < 512; i += 256) {
        s += partials[(b * 512 + i) * 2];
        q += partials[(b * 512 + i) * 2 + 1];
    }
#pragma unroll
    for (int off = 32; off; off >>= 1) {
        s += __shfl_down(s, off);
        q += __shfl_down(q, off);
    }
    __shared__ float rb[8];
    int wid = tid >> 6;
    if ((tid & 63) == 0) { rb[wid * 2] = s; rb[wid * 2 + 1] = q; }
    __syncthreads();
    if (tid == 0) {
        float S = rb[0] + rb[2] + rb[4] + rb[6];
        float Q = rb[1] + rb[3] + rb[5] + rb[7];
        const float N = 2097152.0f;  // 128*16384
        float mean = S / N;
        float var = Q / N - mean * mean;
        stats[b * 2] = mean;
        stats[b * 2 + 1] = rsqrtf(var + 1e-5f);
    }
}

// ---------------- finalize: h_next = o * relu((c_next-mean)*rstd) ----------------
__global__ void final_kernel(float* __restrict__ out, const unsigned short* __restrict__ obuf,
                             const float* __restrict__ stats)
{
    const int n8 = CSLOT / 8;
    const int per_b = 2097152 / 8;
    for (int i = blockIdx.x * blockDim.x + threadIdx.x; i < n8; i += gridDim.x * blockDim.x) {
        int b = i / per_b;
        float mean = stats[b * 2], rstd = stats[b * 2 + 1];
        us8 o8 = *(const us8*)&obuf[(size_t)i * 8];
        float4 c0 = ((const float4*)out)[CSLOT / 4 + i * 2];
        float4 c1 = ((const float4*)out)[CSLOT / 4 + i * 2 + 1];
        float4 h0, h1;
        h0.x = bf2f(o8[0]) * fmaxf((c0.x - mean) * rstd, 0.f);
        h0.y = bf2f(o8[1]) * fmaxf((c0.y - mean) * rstd, 0.f);
        h0.z = bf2f(o8[2]) * fmaxf((c0.z - mean) * rstd, 0.f);
        h0.w = bf2f(o8[3]) * fmaxf((c0.w - mean) * rstd, 0.f);
        h1.x = bf2f(o8[4]) * fmaxf((c1.x - mean) * rstd, 0.f);
        h1.y = bf2f(o8[5]) * fmaxf((c1.y - mean) * rstd, 0.f);
        h1.z = bf2f(o8[6]) * fmaxf((c1.z - mean) * rstd, 0.f);
        h1.w = bf2f(o8[7]) * fmaxf((c1.w - mean) * rstd, 0.f);
        ((float4*)out)[i * 2]     = h0;
        ((float4*)out)[i * 2 + 1] = h1;
    }
}

extern "C" void kernel_launch(void* const* d_in, const int* in_sizes, int n_in,
                              void* d_out, int out_size, void* d_ws, size_t ws_size,
                              hipStream_t stream)
{
    const float* x        = (const float*)d_in[0];
    const float* h        = (const float*)d_in[1];
    const float* c        = (const float*)d_in[2];
    const float* w_xh_dw  = (const float*)d_in[3];
    const float* b_xh_dw  = (const float*)d_in[4];
    const float* w_xh_pw  = (const float*)d_in[5];
    const float* b_xh_pw  = (const float*)d_in[6];
    const float* w_exc_dw = (const float*)d_in[7];
    const float* b_exc_dw = (const float*)d_in[8];
    const float* w_exc_pw = (const float*)d_in[9];
    const float* b_exc_pw = (const float*)d_in[10];
    const float* w_inh_dw = (const float*)d_in[11];
    const float* b_inh_dw = (const float*)d_in[12];
    const float* w_inh_pw = (const float*)d_in[13];
    const float* b_inh_pw = (const float*)d_in[14];

    float* out = (float*)d_out;
    unsigned short* wsu = (unsigned short*)d_ws;

    unsigned short* dxh  = wsu;                       // 33,554,432 ushort (8,256,HW)
    unsigned short* dexc = wsu + 33554432;            // 16,777,216
    unsigned short* dinh = wsu + 50331648;            // 16,777,216
    unsigned short* wbf  = wsu + 67108864;            // 131,072
    unsigned short* obuf = wsu + 67239936;            // 16,777,216
    float* partials = (float*)(wsu + 84017152);       // 8,192 floats
    float* stats    = partials + 8192;                // 16 floats

    wconv_kernel<<<dim3(512), dim3(256), 0, stream>>>(w_xh_pw, w_exc_pw, w_inh_pw, wbf);

    // x depthwise (5x5) -> dxh channels 0..127
    conv_x_kernel<<<dim3(8, 128, 8), dim3(256), 0, stream>>>(x, w_xh_dw, b_xh_dw, dxh);
    // fused h depthwise: 7x7 exc, 5x5 xh(h-part), 5x5 inh — h read once
    conv_h_kernel<<<dim3(8, 128, 8), dim3(256), 0, stream>>>(
        h, w_exc_dw, b_exc_dw, w_xh_dw + 128 * 25, b_xh_dw + 128, w_inh_dw, b_inh_dw,
        dxh, dexc, dinh);

    gate_kernel<<<dim3(4096), dim3(256), 0, stream>>>(
        dxh, dexc, dinh, wbf, b_xh_pw, b_exc_pw, b_inh_pw, c, out, obuf, partials);

    stats_kernel<<<dim3(8), dim3(256), 0, stream>>>(partials, stats);
    final_kernel<<<dim3(2048), dim3(256), 0, stream>>>(out, obuf, stats);
}

// Round 4
// 451.007 us; speedup vs baseline: 2.8953x; 1.0010x over previous
//
#include <hip/hip_runtime.h>
#include <math.h>

#define IMG_W 128
#define HW 16384
#define NCH 128
#define CSLOT 16777216   // 8*128*16384 elements (h_next slot size)

typedef __attribute__((ext_vector_type(8))) short bf16x8;
typedef __attribute__((ext_vector_type(16))) float f32x16;
typedef __attribute__((ext_vector_type(8))) unsigned short us8;

__device__ __forceinline__ float sigmoidf_(float x) { return 1.0f / (1.0f + expf(-x)); }

__device__ __forceinline__ unsigned short f2bf(float f) {
    union { float f; unsigned int u; } x; x.f = f;
    unsigned int r = x.u + 0x7fffu + ((x.u >> 16) & 1u);   // RNE
    return (unsigned short)(r >> 16);
}
__device__ __forceinline__ float bf2f(unsigned short s) {
    union { unsigned int u; float f; } x; x.u = ((unsigned int)s) << 16; return x.f;
}

// =====================================================================
// B-data layout (bf16): [b][y 128][g = ch/8][x 128][c = ch%8]
//   dxh:  G=32 (g 0..15 = x-conv channels, g 16..31 = h-conv xh channels)
//   dexc: G=16 ; dinh: G=16
// A lane's MFMA fragment (8 consecutive k at one px) = 16B contiguous.
// =====================================================================

// ---------------- x depthwise conv 5x5: 8ch/block, 32x16 tile, 2 vert px/thread ----------------
__global__ __launch_bounds__(256) void conv_x_kernel(const float* __restrict__ in,
    const float* __restrict__ w, const float* __restrict__ bias,
    unsigned short* __restrict__ dxh)
{
    __shared__ float t[8][20][40];    // rows y0-2..y0+17, cols x0-2..x0+33
    __shared__ float wsh[208];        // 8*25 weights + 8 bias
    int z = blockIdx.z;
    int b = z >> 4, g = z & 15;
    int x0 = blockIdx.x * 32, y0 = blockIdx.y * 16;
    int tid = threadIdx.x;

    for (int i = tid; i < 200; i += 256) {
        int c = i / 25, r = i % 25;
        wsh[c * 25 + r] = w[(g * 8 + c) * 25 + r];
    }
    if (tid < 8) wsh[200 + tid] = bias[g * 8 + tid];
    for (int i = tid; i < 8 * 20 * 36; i += 256) {
        int c = i / 720, rem = i % 720, r = rem / 36, col = rem % 36;
        int gy = y0 + r - 2, gx = x0 + col - 2;
        float v = 0.f;
        if ((unsigned)gy < 128u && (unsigned)gx < 128u)
            v = in[(size_t)(b * NCH + g * 8 + c) * HW + gy * IMG_W + gx];
        t[c][r][col] = v;
    }
    __syncthreads();

    int xi = tid & 31, ty = tid >> 5;     // ty 0..7, y pair = y0+ty*2, +1
    us8 rX[2];
#pragma unroll
    for (int c = 0; c < 8; ++c) {
        float win[6][5];
#pragma unroll
        for (int rr = 0; rr < 6; ++rr)
#pragma unroll
            for (int cc = 0; cc < 5; ++cc)
                win[rr][cc] = t[c][ty * 2 + rr][xi + cc];
        float a0 = 0.f, a1 = 0.f;
#pragma unroll
        for (int u = 0; u < 5; ++u)
#pragma unroll
            for (int v = 0; v < 5; ++v) {
                float wv = wsh[c * 25 + u * 5 + v];
                a0 += win[u][v] * wv;
                a1 += win[u + 1][v] * wv;
            }
        float bv = wsh[200 + c];
        rX[0][c] = f2bf(a0 + bv);
        rX[1][c] = f2bf(a1 + bv);
    }
#pragma unroll
    for (int p = 0; p < 2; ++p) {
        int y = y0 + ty * 2 + p, x = x0 + xi;
        *(us8*)&dxh[(((size_t)(b * 128 + y) * 32 + g) * 128 + x) * 8] = rX[p];
    }
}

// ---------------- fused h depthwise convs: 7x7(exc) + 5x5(xh) + 5x5(inh), 8ch/block ----------------
__global__ __launch_bounds__(256) void conv_h_kernel(const float* __restrict__ in,
    const float* __restrict__ w7,  const float* __restrict__ b7,
    const float* __restrict__ w5x, const float* __restrict__ b5x,
    const float* __restrict__ w5i, const float* __restrict__ b5i,
    unsigned short* __restrict__ dxh, unsigned short* __restrict__ dexc,
    unsigned short* __restrict__ dinh)
{
    __shared__ float t[8][22][40];    // rows y0-3..y0+18, cols x0-3..x0+34
    __shared__ float wsh[816];        // 8*(49+25+25) + 24 biases
    int z = blockIdx.z;
    int b = z >> 4, g = z & 15;
    int x0 = blockIdx.x * 32, y0 = blockIdx.y * 16;
    int tid = threadIdx.x;

    for (int i = tid; i < 792; i += 256) {
        int c = i / 99, r = i % 99;
        int ch = g * 8 + c;
        float v;
        if (r < 49)      v = w7[ch * 49 + r];
        else if (r < 74) v = w5x[ch * 25 + r - 49];
        else             v = w5i[ch * 25 + r - 74];
        wsh[i] = v;
    }
    if (tid < 24) {
        int c = tid & 7, m = tid >> 3;
        wsh[792 + tid] = (m == 0) ? b7[g * 8 + c] : (m == 1) ? b5x[g * 8 + c] : b5i[g * 8 + c];
    }
    for (int i = tid; i < 8 * 22 * 38; i += 256) {
        int c = i / 836, rem = i % 836, r = rem / 38, col = rem % 38;
        int gy = y0 + r - 3, gx = x0 + col - 3;
        float v = 0.f;
        if ((unsigned)gy < 128u && (unsigned)gx < 128u)
            v = in[(size_t)(b * NCH + g * 8 + c) * HW + gy * IMG_W + gx];
        t[c][r][col] = v;
    }
    __syncthreads();

    int xi = tid & 31, ty = tid >> 5;
    us8 rE[2], rX[2], rI[2];
#pragma unroll
    for (int c = 0; c < 8; ++c) {
        float win[8][7];
#pragma unroll
        for (int rr = 0; rr < 8; ++rr)
#pragma unroll
            for (int cc = 0; cc < 7; ++cc)
                win[rr][cc] = t[c][ty * 2 + rr][xi + cc];
        const int W = c * 99;
        float a7[2] = {}, ax[2] = {}, ai[2] = {};
#pragma unroll
        for (int u = 0; u < 7; ++u)
#pragma unroll
            for (int v = 0; v < 7; ++v) {
                float wv = wsh[W + u * 7 + v];
                a7[0] += win[u][v] * wv;
                a7[1] += win[u + 1][v] * wv;
            }
#pragma unroll
        for (int u = 0; u < 5; ++u)
#pragma unroll
            for (int v = 0; v < 5; ++v) {
                float wx = wsh[W + 49 + u * 5 + v];
                float wi = wsh[W + 74 + u * 5 + v];
                float e0 = win[u + 1][v + 1], e1 = win[u + 2][v + 1];
                ax[0] += e0 * wx; ax[1] += e1 * wx;
                ai[0] += e0 * wi; ai[1] += e1 * wi;
            }
        float bE = wsh[792 + c], bX = wsh[800 + c], bI = wsh[808 + c];
#pragma unroll
        for (int p = 0; p < 2; ++p) {
            rE[p][c] = f2bf(a7[p] + bE);
            rX[p][c] = f2bf(ax[p] + bX);
            rI[p][c] = f2bf(ai[p] + bI);
        }
    }
#pragma unroll
    for (int p = 0; p < 2; ++p) {
        int y = y0 + ty * 2 + p, x = x0 + xi;
        size_t r16 = (size_t)(b * 128 + y) * 16 + g;
        *(us8*)&dexc[(r16 * 128 + x) * 8] = rE[p];
        *(us8*)&dinh[(r16 * 128 + x) * 8] = rI[p];
        *(us8*)&dxh[(((size_t)(b * 128 + y) * 32 + 16 + g) * 128 + x) * 8] = rX[p];
    }
}

// ---------------- pointwise weight prepack: per-lane fragment-linear A' ----------------
// A'[gcT 4][fi 64][lane 64][c 8] bf16.  fi<48: xh (fi = (c0/64)*12 + ks*3 + m);
// 48..55: exc (48 + (c0/64)*4 + ks); 56..63: inh.  k = c0+ks*16+hi*8+c, row = gcT*32+lrow.
__global__ void wconv_kernel(const float* __restrict__ Wxh, const float* __restrict__ Wexc,
                             const float* __restrict__ Winh, unsigned short* __restrict__ A)
{
    int i = blockIdx.x * 256 + threadIdx.x;
    if (i >= 131072) return;
    int c = i & 7, lane = (i >> 3) & 63, fi = (i >> 9) & 63, gcT = i >> 15;
    int hi = lane >> 5, lrow = lane & 31, row = gcT * 32 + lrow;
    float v;
    if (fi < 48) {
        int c0 = (fi / 12) * 64, r = fi % 12, ks = r / 3, m = r % 3;
        v = Wxh[(size_t)(m * 128 + row) * 256 + c0 + ks * 16 + hi * 8 + c];
    } else if (fi < 56) {
        int j = fi - 48, c0 = (j >> 2) * 64, ks = j & 3;
        v = Wexc[(size_t)row * 128 + c0 + ks * 16 + hi * 8 + c];
    } else {
        int j = fi - 56, c0 = (j >> 2) * 64, ks = j & 3;
        v = Winh[(size_t)row * 128 + c0 + ks * 16 + hi * 8 + c];
    }
    A[i] = f2bf(v);
}

// ---------------- register-streaming MFMA gate kernel: no LDS staging, no barriers ----------------
// block = 4 waves; wave w owns px 32w..32w+31 of row y. 32 gc x 128 px per block.
// grid 4096 XCD-swizzled; gcT siblings adjacent on one XCD (B re-read hits L2).
__global__ __launch_bounds__(256) void gate_kernel(
                            const unsigned short* __restrict__ dxh,
                            const unsigned short* __restrict__ dexc,
                            const unsigned short* __restrict__ dinh,
                            const unsigned short* __restrict__ Afrag,
                            const float* __restrict__ bxh,
                            const float* __restrict__ bexc,
                            const float* __restrict__ binh,
                            const float* __restrict__ cin,
                            float* __restrict__ out,
                            unsigned short* __restrict__ obuf,
                            float* __restrict__ partials)
{
    __shared__ float rbuf[8];
    int d = blockIdx.x;
    int orig = (d & 7) * 512 + (d >> 3);
    int b = orig >> 9, y = (orig >> 2) & 127, gcT = orig & 3;
    int gc0 = gcT * 32;
    int tid = threadIdx.x, lane = tid & 63, w = tid >> 6;
    int hi = lane >> 5, lrow = lane & 31;
    int pxl = (w << 5) + lrow;

    f32x16 accF = {}, accG = {}, accO = {}, accE = {}, accI = {};

    const us8* Ab = (const us8*)Afrag + (size_t)gcT * 4096 + lane;        // + fi*64
    const us8* Bx = (const us8*)dxh  + ((size_t)(b * 128 + y) * 32) * 128 + pxl;  // + gidx*128
    const us8* Be = (const us8*)dexc + ((size_t)(b * 128 + y) * 16) * 128 + pxl;
    const us8* Bi = (const us8*)dinh + ((size_t)(b * 128 + y) * 16) * 128 + pxl;

    // ---- phase 1: xh GEMM, K=256 ----
    for (int c0i = 0; c0i < 4; ++c0i) {
#pragma unroll
        for (int ks = 0; ks < 4; ++ks) {
            int gidx = c0i * 8 + ks * 2 + hi;
            bf16x8 bf = *(const bf16x8*)(Bx + gidx * 128);
            int fi = c0i * 12 + ks * 3;
            bf16x8 aF = *(const bf16x8*)(Ab + fi * 64);
            bf16x8 aG = *(const bf16x8*)(Ab + (fi + 1) * 64);
            bf16x8 aO = *(const bf16x8*)(Ab + (fi + 2) * 64);
            accF = __builtin_amdgcn_mfma_f32_32x32x16_bf16(aF, bf, accF, 0, 0, 0);
            accG = __builtin_amdgcn_mfma_f32_32x32x16_bf16(aG, bf, accG, 0, 0, 0);
            accO = __builtin_amdgcn_mfma_f32_32x32x16_bf16(aO, bf, accO, 0, 0, 0);
        }
    }
    // ---- phase 2: exc GEMM, K=128 ----
    for (int c0i = 0; c0i < 2; ++c0i) {
#pragma unroll
        for (int ks = 0; ks < 4; ++ks) {
            int gidx = c0i * 8 + ks * 2 + hi;
            bf16x8 bf = *(const bf16x8*)(Be + gidx * 128);
            bf16x8 aE = *(const bf16x8*)(Ab + (48 + c0i * 4 + ks) * 64);
            accE = __builtin_amdgcn_mfma_f32_32x32x16_bf16(aE, bf, accE, 0, 0, 0);
        }
    }
    // ---- phase 3: inh GEMM, K=128 ----
    for (int c0i = 0; c0i < 2; ++c0i) {
#pragma unroll
        for (int ks = 0; ks < 4; ++ks) {
            int gidx = c0i * 8 + ks * 2 + hi;
            bf16x8 bf = *(const bf16x8*)(Bi + gidx * 128);
            bf16x8 aI = *(const bf16x8*)(Ab + (56 + c0i * 4 + ks) * 64);
            accI = __builtin_amdgcn_mfma_f32_32x32x16_bf16(aI, bf, accI, 0, 0, 0);
        }
    }

    // ---- epilogue: gating, c_next, stash o (bf16), partial LN sums ----
    float lsum = 0.f, lsq = 0.f;
#pragma unroll
    for (int r = 0; r < 16; ++r) {
        int row = (r & 3) + 8 * (r >> 2) + 4 * hi;   // verified 32x32 C/D map
        int gc = gc0 + row;
        size_t idx = ((size_t)(b * NCH + gc)) * HW + y * IMG_W + pxl;
        float f    = sigmoidf_(accF[r] + bxh[gc]);
        float o    = sigmoidf_(accO[r] + bxh[gc + 256]);
        float xhor = fmaxf(accG[r] + bxh[gc + 128], 0.f);
        float g    = sigmoidf_(accI[r] + binh[gc]) * (xhor + sigmoidf_(accE[r] + bexc[gc]));
        float cn   = f * cin[idx] + (1.f - f) * g;
        out[CSLOT + idx] = cn;
        obuf[idx] = f2bf(o);
        lsum += cn; lsq += cn * cn;
    }

#pragma unroll
    for (int off = 32; off; off >>= 1) {
        lsum += __shfl_down(lsum, off);
        lsq  += __shfl_down(lsq, off);
    }
    if ((tid & 63) == 0) { rbuf[w * 2] = lsum; rbuf[w * 2 + 1] = lsq; }
    __syncthreads();
    if (tid == 0) {
        float s = rbuf[0] + rbuf[2] + rbuf[4] + rbuf[6];
        float q = rbuf[1] + rbuf[3] + rbuf[5] + rbuf[7];
        int blin = b * 512 + gcT * 128 + y;
        partials[blin * 2]     = s;
        partials[blin * 2 + 1] = q;
    }
}

// ---------------- per-sample LN statistics ----------------
__global__ void stats_kernel(const float* __restrict__ partials, float* __restrict__ stats)
{
    int b = blockIdx.x;
    int tid = threadIdx.x;
    float s = 0.f, q = 0.f;
    for (int i = tid; i < 512; i += 256) {
        s += partials[(b * 512 + i) * 2];
        q += partials[(b * 512 + i) * 2 + 1];
    }
#pragma unroll
    for (int off = 32; off; off >>= 1) {
        s += __shfl_down(s, off);
        q += __shfl_down(q, off);
    }
    __shared__ float rb[8];
    int wid = tid >> 6;
    if ((tid & 63) == 0) { rb[wid * 2] = s; rb[wid * 2 + 1] = q; }
    __syncthreads();
    if (tid == 0) {
        float S = rb[0] + rb[2] + rb[4] + rb[6];
        float Q = rb[1] + rb[3] + rb[5] + rb[7];
        const float N = 2097152.0f;
        float mean = S / N;
        float var = Q / N - mean * mean;
        stats[b * 2] = mean;
        stats[b * 2 + 1] = rsqrtf(var + 1e-5f);
    }
}

// ---------------- finalize: h_next = o * relu((c_next-mean)*rstd) ----------------
__global__ void final_kernel(float* __restrict__ out, const unsigned short* __restrict__ obuf,
                             const float* __restrict__ stats)
{
    const int n8 = CSLOT / 8;
    const int per_b = 2097152 / 8;
    for (int i = blockIdx.x * blockDim.x + threadIdx.x; i < n8; i += gridDim.x * blockDim.x) {
        int b = i / per_b;
        float mean = stats[b * 2], rstd = stats[b * 2 + 1];
        us8 o8 = *(const us8*)&obuf[(size_t)i * 8];
        float4 c0 = ((const float4*)out)[CSLOT / 4 + i * 2];
        float4 c1 = ((const float4*)out)[CSLOT / 4 + i * 2 + 1];
        float4 h0, h1;
        h0.x = bf2f(o8[0]) * fmaxf((c0.x - mean) * rstd, 0.f);
        h0.y = bf2f(o8[1]) * fmaxf((c0.y - mean) * rstd, 0.f);
        h0.z = bf2f(o8[2]) * fmaxf((c0.z - mean) * rstd, 0.f);
        h0.w = bf2f(o8[3]) * fmaxf((c0.w - mean) * rstd, 0.f);
        h1.x = bf2f(o8[4]) * fmaxf((c1.x - mean) * rstd, 0.f);
        h1.y = bf2f(o8[5]) * fmaxf((c1.y - mean) * rstd, 0.f);
        h1.z = bf2f(o8[6]) * fmaxf((c1.z - mean) * rstd, 0.f);
        h1.w = bf2f(o8[7]) * fmaxf((c1.w - mean) * rstd, 0.f);
        ((float4*)out)[i * 2]     = h0;
        ((float4*)out)[i * 2 + 1] = h1;
    }
}

extern "C" void kernel_launch(void* const* d_in, const int* in_sizes, int n_in,
                              void* d_out, int out_size, void* d_ws, size_t ws_size,
                              hipStream_t stream)
{
    const float* x        = (const float*)d_in[0];
    const float* h        = (const float*)d_in[1];
    const float* c        = (const float*)d_in[2];
    const float* w_xh_dw  = (const float*)d_in[3];
    const float* b_xh_dw  = (const float*)d_in[4];
    const float* w_xh_pw  = (const float*)d_in[5];
    const float* b_xh_pw  = (const float*)d_in[6];
    const float* w_exc_dw = (const float*)d_in[7];
    const float* b_exc_dw = (const float*)d_in[8];
    const float* w_exc_pw = (const float*)d_in[9];
    const float* b_exc_pw = (const float*)d_in[10];
    const float* w_inh_dw = (const float*)d_in[11];
    const float* b_inh_dw = (const float*)d_in[12];
    const float* w_inh_pw = (const float*)d_in[13];
    const float* b_inh_pw = (const float*)d_in[14];

    float* out = (float*)d_out;
    unsigned short* wsu = (unsigned short*)d_ws;

    unsigned short* dxh   = wsu;                      // 33,554,432 u16
    unsigned short* dexc  = wsu + 33554432;           // 16,777,216
    unsigned short* dinh  = wsu + 50331648;           // 16,777,216
    unsigned short* Afrag = wsu + 67108864;           // 131,072
    unsigned short* obuf  = wsu + 67239936;           // 16,777,216
    float* partials = (float*)(wsu + 84017152);       // 8,192 floats
    float* stats    = partials + 8192;                // 16 floats

    wconv_kernel<<<dim3(512), dim3(256), 0, stream>>>(w_xh_pw, w_exc_pw, w_inh_pw, Afrag);

    conv_x_kernel<<<dim3(4, 8, 128), dim3(256), 0, stream>>>(x, w_xh_dw, b_xh_dw, dxh);
    conv_h_kernel<<<dim3(4, 8, 128), dim3(256), 0, stream>>>(
        h, w_exc_dw, b_exc_dw, w_xh_dw + 128 * 25, b_xh_dw + 128, w_inh_dw, b_inh_dw,
        dxh, dexc, dinh);

    gate_kernel<<<dim3(4096), dim3(256), 0, stream>>>(
        dxh, dexc, dinh, Afrag, b_xh_pw, b_exc_pw, b_inh_pw, c, out, obuf, partials);

    stats_kernel<<<dim3(8), dim3(256), 0, stream>>>(partials, stats);
    final_kernel<<<dim3(2048), dim3(256), 0, stream>>>(out, obuf, stats);
}

// Round 5
// 392.555 us; speedup vs baseline: 3.3264x; 1.1489x over previous
//
#include <hip/hip_runtime.h>
#include <math.h>

#define IMG_W 128
#define HW 16384
#define NCH 128
#define CSLOT 16777216   // 8*128*16384 elements (h_next slot size)

typedef __attribute__((ext_vector_type(8))) short bf16x8;
typedef __attribute__((ext_vector_type(16))) float f32x16;
typedef __attribute__((ext_vector_type(8))) unsigned short us8;

__device__ __forceinline__ float sigmoidf_(float x) { return 1.0f / (1.0f + expf(-x)); }

__device__ __forceinline__ unsigned short f2bf(float f) {
    union { float f; unsigned int u; } x; x.f = f;
    unsigned int r = x.u + 0x7fffu + ((x.u >> 16) & 1u);   // RNE
    return (unsigned short)(r >> 16);
}
__device__ __forceinline__ float bf2f(unsigned short s) {
    union { unsigned int u; float f; } x; x.u = ((unsigned int)s) << 16; return x.f;
}

// =====================================================================
// B-data layout (bf16): [b][y 128][g = ch/8][x 128][c = ch%8]
//   dxh:  G=32 (g 0..15 = x-conv channels, g 16..31 = h-conv xh channels)
//   dexc: G=16 ; dinh: G=16
// =====================================================================

// ---------------- x depthwise conv 5x5 ----------------
// block: 8 ch x (32x8) px tile; thread = (c, txq, ty): 8 horizontal px, 1 row, 1 ch.
__global__ __launch_bounds__(256) void conv_x_kernel(const float* __restrict__ in,
    const float* __restrict__ w, const float* __restrict__ bias,
    unsigned short* __restrict__ dxh)
{
    __shared__ float t[8][12][40];    // rows y0-2..y0+9, cols x0-2..x0+33
    __shared__ float wsh[208];        // 8*25 + 8 bias
    int z = blockIdx.z;
    int b = z >> 4, g = z & 15;
    int x0 = blockIdx.x * 32, y0 = blockIdx.y * 8;
    int tid = threadIdx.x;

    for (int i = tid; i < 200; i += 256) {
        int c = i / 25, r = i % 25;
        wsh[c * 25 + r] = w[(g * 8 + c) * 25 + r];
    }
    if (tid < 8) wsh[200 + tid] = bias[g * 8 + tid];
    for (int i = tid; i < 8 * 12 * 38; i += 256) {
        int c = i / 456, rem = i % 456, r = rem / 38, col = rem % 38;
        int gy = y0 + r - 2, gx = x0 + col - 2;
        float v = 0.f;
        if ((unsigned)gy < 128u && (unsigned)gx < 128u)
            v = in[(size_t)(b * NCH + g * 8 + c) * HW + gy * IMG_W + gx];
        t[c][r][col] = v;
    }
    __syncthreads();

    int c = tid & 7, txq = (tid >> 3) & 3, ty = tid >> 5;
    int tx = txq * 8;
    float acc[8] = {};
#pragma unroll
    for (int u = 0; u < 5; ++u) {
        float win[12];
        *(float4*)&win[0] = *(const float4*)&t[c][ty + u][tx];
        *(float4*)&win[4] = *(const float4*)&t[c][ty + u][tx + 4];
        *(float4*)&win[8] = *(const float4*)&t[c][ty + u][tx + 8];
#pragma unroll
        for (int v = 0; v < 5; ++v) {
            float wv = wsh[c * 25 + u * 5 + v];
#pragma unroll
            for (int j = 0; j < 8; ++j) acc[j] += win[j + v] * wv;
        }
    }
    float bv = wsh[200 + c];
    int y = y0 + ty;
    unsigned short* dst = &dxh[(((size_t)(b * 128 + y) * 32 + g) * 128 + x0 + tx) * 8 + c];
#pragma unroll
    for (int j = 0; j < 8; ++j) dst[j * 8] = f2bf(acc[j] + bv);
}

// ---------------- fused h depthwise convs: 7x7(exc) + 5x5(xh) + 5x5(inh) ----------------
// block: 8 ch x (32x8) px tile; thread = 8 horizontal px, 1 row, 1 ch, 3 convs.
__global__ __launch_bounds__(256) void conv_h_kernel(const float* __restrict__ in,
    const float* __restrict__ w7,  const float* __restrict__ b7,
    const float* __restrict__ w5x, const float* __restrict__ b5x,
    const float* __restrict__ w5i, const float* __restrict__ b5i,
    unsigned short* __restrict__ dxh, unsigned short* __restrict__ dexc,
    unsigned short* __restrict__ dinh)
{
    __shared__ float t[8][14][40];    // rows y0-3..y0+10, cols x0-3..x0+34
    __shared__ float wsh[816];        // 8*(49+25+25) + 24 biases
    int z = blockIdx.z;
    int b = z >> 4, g = z & 15;
    int x0 = blockIdx.x * 32, y0 = blockIdx.y * 8;
    int tid = threadIdx.x;

    for (int i = tid; i < 792; i += 256) {
        int c = i / 99, r = i % 99;
        int ch = g * 8 + c;
        float v;
        if (r < 49)      v = w7[ch * 49 + r];
        else if (r < 74) v = w5x[ch * 25 + r - 49];
        else             v = w5i[ch * 25 + r - 74];
        wsh[i] = v;
    }
    if (tid < 24) {
        int c = tid & 7, m = tid >> 3;
        wsh[792 + tid] = (m == 0) ? b7[g * 8 + c] : (m == 1) ? b5x[g * 8 + c] : b5i[g * 8 + c];
    }
    for (int i = tid; i < 8 * 14 * 38; i += 256) {
        int c = i / 532, rem = i % 532, r = rem / 38, col = rem % 38;
        int gy = y0 + r - 3, gx = x0 + col - 3;
        float v = 0.f;
        if ((unsigned)gy < 128u && (unsigned)gx < 128u)
            v = in[(size_t)(b * NCH + g * 8 + c) * HW + gy * IMG_W + gx];
        t[c][r][col] = v;
    }
    __syncthreads();

    int c = tid & 7, txq = (tid >> 3) & 3, ty = tid >> 5;
    int tx = txq * 8;
    const int W = c * 99;
    float a7[8] = {}, ax[8] = {}, ai[8] = {};
#pragma unroll
    for (int u = 0; u < 7; ++u) {
        float win[16];
        *(float4*)&win[0]  = *(const float4*)&t[c][ty + u][tx];
        *(float4*)&win[4]  = *(const float4*)&t[c][ty + u][tx + 4];
        *(float4*)&win[8]  = *(const float4*)&t[c][ty + u][tx + 8];
        *(float4*)&win[12] = *(const float4*)&t[c][ty + u][tx + 12];
#pragma unroll
        for (int v = 0; v < 7; ++v) {
            float wv = wsh[W + u * 7 + v];
#pragma unroll
            for (int j = 0; j < 8; ++j) a7[j] += win[j + v] * wv;
        }
        if (u >= 1 && u <= 5) {
#pragma unroll
            for (int v = 0; v < 5; ++v) {
                float wx = wsh[W + 49 + (u - 1) * 5 + v];
                float wi = wsh[W + 74 + (u - 1) * 5 + v];
#pragma unroll
                for (int j = 0; j < 8; ++j) {
                    float e = win[j + v + 1];
                    ax[j] += e * wx;
                    ai[j] += e * wi;
                }
            }
        }
    }
    float bE = wsh[792 + c], bX = wsh[800 + c], bI = wsh[808 + c];
    int y = y0 + ty;
    size_t r16 = ((size_t)(b * 128 + y) * 16 + g) * 128 + x0 + tx;
    unsigned short* dE = &dexc[r16 * 8 + c];
    unsigned short* dI = &dinh[r16 * 8 + c];
    unsigned short* dX = &dxh[(((size_t)(b * 128 + y) * 32 + 16 + g) * 128 + x0 + tx) * 8 + c];
#pragma unroll
    for (int j = 0; j < 8; ++j) {
        dE[j * 8] = f2bf(a7[j] + bE);
        dX[j * 8] = f2bf(ax[j] + bX);
        dI[j * 8] = f2bf(ai[j] + bI);
    }
}

// ---------------- pointwise weight prepack: per-lane fragment-linear A' ----------------
// A'[gcT 4][fi 64][lane 64][c 8] bf16.  fi<48: xh (fi = (c0/64)*12 + ks*3 + m);
// 48..55: exc; 56..63: inh.  k = c0+ks*16+hi*8+c, row = gcT*32+lrow.
__global__ void wconv_kernel(const float* __restrict__ Wxh, const float* __restrict__ Wexc,
                             const float* __restrict__ Winh, unsigned short* __restrict__ A)
{
    int i = blockIdx.x * 256 + threadIdx.x;
    if (i >= 131072) return;
    int c = i & 7, lane = (i >> 3) & 63, fi = (i >> 9) & 63, gcT = i >> 15;
    int hi = lane >> 5, lrow = lane & 31, row = gcT * 32 + lrow;
    float v;
    if (fi < 48) {
        int c0 = (fi / 12) * 64, r = fi % 12, ks = r / 3, m = r % 3;
        v = Wxh[(size_t)(m * 128 + row) * 256 + c0 + ks * 16 + hi * 8 + c];
    } else if (fi < 56) {
        int j = fi - 48, c0 = (j >> 2) * 64, ks = j & 3;
        v = Wexc[(size_t)row * 128 + c0 + ks * 16 + hi * 8 + c];
    } else {
        int j = fi - 56, c0 = (j >> 2) * 64, ks = j & 3;
        v = Winh[(size_t)row * 128 + c0 + ks * 16 + hi * 8 + c];
    }
    A[i] = f2bf(v);
}

// ---------------- register-streaming MFMA gate kernel: no LDS staging, no barriers ----------------
__global__ __launch_bounds__(256) void gate_kernel(
                            const unsigned short* __restrict__ dxh,
                            const unsigned short* __restrict__ dexc,
                            const unsigned short* __restrict__ dinh,
                            const unsigned short* __restrict__ Afrag,
                            const float* __restrict__ bxh,
                            const float* __restrict__ bexc,
                            const float* __restrict__ binh,
                            const float* __restrict__ cin,
                            float* __restrict__ out,
                            unsigned short* __restrict__ obuf,
                            float* __restrict__ partials)
{
    __shared__ float rbuf[8];
    int d = blockIdx.x;
    int orig = (d & 7) * 512 + (d >> 3);
    int b = orig >> 9, y = (orig >> 2) & 127, gcT = orig & 3;
    int gc0 = gcT * 32;
    int tid = threadIdx.x, lane = tid & 63, w = tid >> 6;
    int hi = lane >> 5, lrow = lane & 31;
    int pxl = (w << 5) + lrow;

    f32x16 accF = {}, accG = {}, accO = {}, accE = {}, accI = {};

    const us8* Ab = (const us8*)Afrag + (size_t)gcT * 4096 + lane;
    const us8* Bx = (const us8*)dxh  + ((size_t)(b * 128 + y) * 32) * 128 + pxl;
    const us8* Be = (const us8*)dexc + ((size_t)(b * 128 + y) * 16) * 128 + pxl;
    const us8* Bi = (const us8*)dinh + ((size_t)(b * 128 + y) * 16) * 128 + pxl;

    for (int c0i = 0; c0i < 4; ++c0i) {
#pragma unroll
        for (int ks = 0; ks < 4; ++ks) {
            int gidx = c0i * 8 + ks * 2 + hi;
            bf16x8 bf = *(const bf16x8*)(Bx + gidx * 128);
            int fi = c0i * 12 + ks * 3;
            bf16x8 aF = *(const bf16x8*)(Ab + fi * 64);
            bf16x8 aG = *(const bf16x8*)(Ab + (fi + 1) * 64);
            bf16x8 aO = *(const bf16x8*)(Ab + (fi + 2) * 64);
            accF = __builtin_amdgcn_mfma_f32_32x32x16_bf16(aF, bf, accF, 0, 0, 0);
            accG = __builtin_amdgcn_mfma_f32_32x32x16_bf16(aG, bf, accG, 0, 0, 0);
            accO = __builtin_amdgcn_mfma_f32_32x32x16_bf16(aO, bf, accO, 0, 0, 0);
        }
    }
    for (int c0i = 0; c0i < 2; ++c0i) {
#pragma unroll
        for (int ks = 0; ks < 4; ++ks) {
            int gidx = c0i * 8 + ks * 2 + hi;
            bf16x8 bf = *(const bf16x8*)(Be + gidx * 128);
            bf16x8 aE = *(const bf16x8*)(Ab + (48 + c0i * 4 + ks) * 64);
            accE = __builtin_amdgcn_mfma_f32_32x32x16_bf16(aE, bf, accE, 0, 0, 0);
        }
    }
    for (int c0i = 0; c0i < 2; ++c0i) {
#pragma unroll
        for (int ks = 0; ks < 4; ++ks) {
            int gidx = c0i * 8 + ks * 2 + hi;
            bf16x8 bf = *(const bf16x8*)(Bi + gidx * 128);
            bf16x8 aI = *(const bf16x8*)(Ab + (56 + c0i * 4 + ks) * 64);
            accI = __builtin_amdgcn_mfma_f32_32x32x16_bf16(aI, bf, accI, 0, 0, 0);
        }
    }

    float lsum = 0.f, lsq = 0.f;
#pragma unroll
    for (int r = 0; r < 16; ++r) {
        int row = (r & 3) + 8 * (r >> 2) + 4 * hi;   // verified 32x32 C/D map
        int gc = gc0 + row;
        size_t idx = ((size_t)(b * NCH + gc)) * HW + y * IMG_W + pxl;
        float f    = sigmoidf_(accF[r] + bxh[gc]);
        float o    = sigmoidf_(accO[r] + bxh[gc + 256]);
        float xhor = fmaxf(accG[r] + bxh[gc + 128], 0.f);
        float g    = sigmoidf_(accI[r] + binh[gc]) * (xhor + sigmoidf_(accE[r] + bexc[gc]));
        float cn   = f * cin[idx] + (1.f - f) * g;
        out[CSLOT + idx] = cn;
        obuf[idx] = f2bf(o);
        lsum += cn; lsq += cn * cn;
    }

#pragma unroll
    for (int off = 32; off; off >>= 1) {
        lsum += __shfl_down(lsum, off);
        lsq  += __shfl_down(lsq, off);
    }
    if ((tid & 63) == 0) { rbuf[w * 2] = lsum; rbuf[w * 2 + 1] = lsq; }
    __syncthreads();
    if (tid == 0) {
        float s = rbuf[0] + rbuf[2] + rbuf[4] + rbuf[6];
        float q = rbuf[1] + rbuf[3] + rbuf[5] + rbuf[7];
        int blin = b * 512 + gcT * 128 + y;
        partials[blin * 2]     = s;
        partials[blin * 2 + 1] = q;
    }
}

// ---------------- per-sample LN statistics ----------------
__global__ void stats_kernel(const float* __restrict__ partials, float* __restrict__ stats)
{
    int b = blockIdx.x;
    int tid = threadIdx.x;
    float s = 0.f, q = 0.f;
    for (int i = tid; i < 512; i += 256) {
        s += partials[(b * 512 + i) * 2];
        q += partials[(b * 512 + i) * 2 + 1];
    }
#pragma unroll
    for (int off = 32; off; off >>= 1) {
        s += __shfl_down(s, off);
        q += __shfl_down(q, off);
    }
    __shared__ float rb[8];
    int wid = tid >> 6;
    if ((tid & 63) == 0) { rb[wid * 2] = s; rb[wid * 2 + 1] = q; }
    __syncthreads();
    if (tid == 0) {
        float S = rb[0] + rb[2] + rb[4] + rb[6];
        float Q = rb[1] + rb[3] + rb[5] + rb[7];
        const float N = 2097152.0f;
        float mean = S / N;
        float var = Q / N - mean * mean;
        stats[b * 2] = mean;
        stats[b * 2 + 1] = rsqrtf(var + 1e-5f);
    }
}

// ---------------- finalize: h_next = o * relu((c_next-mean)*rstd) ----------------
__global__ void final_kernel(float* __restrict__ out, const unsigned short* __restrict__ obuf,
                             const float* __restrict__ stats)
{
    const int n8 = CSLOT / 8;
    const int per_b = 2097152 / 8;
    for (int i = blockIdx.x * blockDim.x + threadIdx.x; i < n8; i += gridDim.x * blockDim.x) {
        int b = i / per_b;
        float mean = stats[b * 2], rstd = stats[b * 2 + 1];
        us8 o8 = *(const us8*)&obuf[(size_t)i * 8];
        float4 c0 = ((const float4*)out)[CSLOT / 4 + i * 2];
        float4 c1 = ((const float4*)out)[CSLOT / 4 + i * 2 + 1];
        float4 h0, h1;
        h0.x = bf2f(o8[0]) * fmaxf((c0.x - mean) * rstd, 0.f);
        h0.y = bf2f(o8[1]) * fmaxf((c0.y - mean) * rstd, 0.f);
        h0.z = bf2f(o8[2]) * fmaxf((c0.z - mean) * rstd, 0.f);
        h0.w = bf2f(o8[3]) * fmaxf((c0.w - mean) * rstd, 0.f);
        h1.x = bf2f(o8[4]) * fmaxf((c1.x - mean) * rstd, 0.f);
        h1.y = bf2f(o8[5]) * fmaxf((c1.y - mean) * rstd, 0.f);
        h1.z = bf2f(o8[6]) * fmaxf((c1.z - mean) * rstd, 0.f);
        h1.w = bf2f(o8[7]) * fmaxf((c1.w - mean) * rstd, 0.f);
        ((float4*)out)[i * 2]     = h0;
        ((float4*)out)[i * 2 + 1] = h1;
    }
}

extern "C" void kernel_launch(void* const* d_in, const int* in_sizes, int n_in,
                              void* d_out, int out_size, void* d_ws, size_t ws_size,
                              hipStream_t stream)
{
    const float* x        = (const float*)d_in[0];
    const float* h        = (const float*)d_in[1];
    const float* c        = (const float*)d_in[2];
    const float* w_xh_dw  = (const float*)d_in[3];
    const float* b_xh_dw  = (const float*)d_in[4];
    const float* w_xh_pw  = (const float*)d_in[5];
    const float* b_xh_pw  = (const float*)d_in[6];
    const float* w_exc_dw = (const float*)d_in[7];
    const float* b_exc_dw = (const float*)d_in[8];
    const float* w_exc_pw = (const float*)d_in[9];
    const float* b_exc_pw = (const float*)d_in[10];
    const float* w_inh_dw = (const float*)d_in[11];
    const float* b_inh_dw = (const float*)d_in[12];
    const float* w_inh_pw = (const float*)d_in[13];
    const float* b_inh_pw = (const float*)d_in[14];

    float* out = (float*)d_out;
    unsigned short* wsu = (unsigned short*)d_ws;

    unsigned short* dxh   = wsu;                      // 33,554,432 u16
    unsigned short* dexc  = wsu + 33554432;           // 16,777,216
    unsigned short* dinh  = wsu + 50331648;           // 16,777,216
    unsigned short* Afrag = wsu + 67108864;           // 131,072
    unsigned short* obuf  = wsu + 67239936;           // 16,777,216
    float* partials = (float*)(wsu + 84017152);       // 8,192 floats
    float* stats    = partials + 8192;                // 16 floats

    wconv_kernel<<<dim3(512), dim3(256), 0, stream>>>(w_xh_pw, w_exc_pw, w_inh_pw, Afrag);

    conv_x_kernel<<<dim3(4, 16, 128), dim3(256), 0, stream>>>(x, w_xh_dw, b_xh_dw, dxh);
    conv_h_kernel<<<dim3(4, 16, 128), dim3(256), 0, stream>>>(
        h, w_exc_dw, b_exc_dw, w_xh_dw + 128 * 25, b_xh_dw + 128, w_inh_dw, b_inh_dw,
        dxh, dexc, dinh);

    gate_kernel<<<dim3(4096), dim3(256), 0, stream>>>(
        dxh, dexc, dinh, Afrag, b_xh_pw, b_exc_pw, b_inh_pw, c, out, obuf, partials);

    stats_kernel<<<dim3(8), dim3(256), 0, stream>>>(partials, stats);
    final_kernel<<<dim3(2048), dim3(256), 0, stream>>>(out, obuf, stats);
}